// Round 2
// baseline (354.422 us; speedup 1.0000x reference)
//
#include <hip/hip_runtime.h>
#include <math.h>

#define NB 16
#define NC 64
#define NN 1024
#define NK 9
#define NH 4
#define NF 15

// ---- workspace layout (float offsets), total 6391808 floats = 24.4 MB ----
#define OFF_HN     0              /* hnorm [16][64][1024] = 1048576 */
#define OFF_SQV    1048576        /* [16*1024] */
#define OFF_IDX    1064960        /* int[16*1024*9] = 147456 */
#define OFF_DEN1   1212416        /* [4*16*1024] */
#define OFF_U1     1277952        /* [4*16*16] */
#define OFF_DEN2   1278976        /* [16*1024] */
#define OFF_U2     1295360        /* [16*64] */
#define OFF_F11    1296384        /* [4*16*1024] */
#define OFF_F21    1361920
#define OFF_F12    1427456        /* [16*1024] */
#define OFF_F22    1443840
#define OFF_E1     1460224        /* [589824] */
#define OFF_E2     2050048        /* [147456] */
#define OFF_BIG    2197504
#define OFF_DIST   OFF_BIG        /* chunk: 4*1024*1024 floats, dead after knn loop */
#define OFF_WH1    OFF_BIG        /* [4*16*1024*16] = 1048576 */
#define OFF_HCAT   3246080        /* [16*1024*64] */
#define OFF_WH2    4294656        /* [16*1024*64] */
#define OFF_YTIL   5343232        /* [16*1024*64] */
#define ZERO_BASE  OFF_DEN1
#define ZERO_LEN   83968          /* den1+u1+den2+u2, contiguous */

__device__ __forceinline__ unsigned fkey(float x){
  unsigned b = __float_as_uint(x);
  return (b & 0x80000000u) ? ~b : (b | 0x80000000u);   // order-preserving float->uint
}
__device__ __forceinline__ float eluf(float x){ return x > 0.f ? x : expm1f(x); }

// ---------------- K0: zero accumulators ----------------
__global__ __launch_bounds__(256) void k0_zero(float* ws){
  int t = blockIdx.x*256 + threadIdx.x;
  if (t < ZERO_LEN) ws[ZERO_BASE + t] = 0.f;
}

// ---------------- K1: h = x / max(||x||,eps)  (IEEE div, matches ref) ----------------
__global__ __launch_bounds__(256) void k1_norm(const float* __restrict__ x,
                                               float* __restrict__ hn, float* __restrict__ sqv){
  int t = blockIdx.x*256 + threadIdx.x;     // b*NN+n
  int b = t >> 10, n = t & 1023;
  const float* xb = x + b*NC*NN;
  float* hb = hn + b*NC*NN;
  float s = 0.f;
  #pragma unroll
  for (int c = 0; c < NC; c++){ float v = xb[c*NN + n]; s = fmaf(v, v, s); }
  float nrm = fmaxf(sqrtf(s), 1e-12f);
  float s2 = 0.f;
  #pragma unroll
  for (int c = 0; c < NC; c++){
    float v = xb[c*NN + n] / nrm;           // true IEEE division, like the reference
    hb[c*NN + n] = v;
    s2 = fmaf(v, v, s2);                    // same fmaf chain order as k2a's diag dot
  }
  sqv[t] = s2;
}

// ---------------- K2a: dist tile GEMM (128x128 tile, K=64 staged once) ----------------
__global__ __launch_bounds__(256) void k2a_dist(const float* __restrict__ hn,
    const float* __restrict__ sqv, float* __restrict__ dist, int bbase){
  __shared__ float As[64][128];
  __shared__ float Bs[64][128];
  int b = bbase + blockIdx.y;
  int i0 = (blockIdx.x >> 3) * 128, j0 = (blockIdx.x & 7) * 128;
  const float* hb = hn + b*NC*NN;
  for (int t = threadIdx.x; t < 64*128; t += 256){
    int c = t >> 7, ii = t & 127;
    As[c][ii] = hb[c*NN + i0 + ii];
    Bs[c][ii] = hb[c*NN + j0 + ii];
  }
  __syncthreads();
  int tx = threadIdx.x & 15, ty = threadIdx.x >> 4;
  float acc[8][8];
  #pragma unroll
  for (int q = 0; q < 8; q++)
    #pragma unroll
    for (int jj = 0; jj < 8; jj++) acc[q][jj] = 0.f;
  #pragma unroll 4
  for (int c = 0; c < 64; c++){
    float4 a0 = *(const float4*)&As[c][ty*8];
    float4 a1 = *(const float4*)&As[c][ty*8+4];
    float4 b0 = *(const float4*)&Bs[c][tx*8];
    float4 b1 = *(const float4*)&Bs[c][tx*8+4];
    float av[8], bv[8];
    av[0]=a0.x; av[1]=a0.y; av[2]=a0.z; av[3]=a0.w; av[4]=a1.x; av[5]=a1.y; av[6]=a1.z; av[7]=a1.w;
    bv[0]=b0.x; bv[1]=b0.y; bv[2]=b0.z; bv[3]=b0.w; bv[4]=b1.x; bv[5]=b1.y; bv[6]=b1.z; bv[7]=b1.w;
    #pragma unroll
    for (int q = 0; q < 8; q++)
      #pragma unroll
      for (int jj = 0; jj < 8; jj++) acc[q][jj] = fmaf(av[q], bv[jj], acc[q][jj]);
  }
  const float* sv = sqv + b*NN;
  float sj[8];
  #pragma unroll
  for (int jj = 0; jj < 8; jj++) sj[jj] = sv[j0 + tx*8 + jj];
  #pragma unroll
  for (int q = 0; q < 8; q++){
    float si = sv[i0 + ty*8 + q];
    float o0[8];
    #pragma unroll
    for (int jj = 0; jj < 8; jj++) o0[jj] = (si - 2.f*acc[q][jj]) + sj[jj];  // exact +0 on diag
    float* dp = dist + (size_t)((blockIdx.y*NN) + i0 + ty*8 + q)*NN + j0 + tx*8;
    *(float4*)&dp[0] = make_float4(o0[0],o0[1],o0[2],o0[3]);
    *(float4*)&dp[4] = make_float4(o0[4],o0[5],o0[6],o0[7]);
  }
}

// ---------------- K2b: top-9 per row (wave-resident u64 keys, stable ties) ----------------
__global__ __launch_bounds__(256) void k2b_top9(const float* __restrict__ dist,
                                                int* __restrict__ idxb, int bbase){
  int wave = threadIdx.x >> 6, lane = threadIdx.x & 63;
  int rlocal = blockIdx.x*4 + wave;          // chunk-local row (4 batches * 1024)
  int bl = rlocal >> 10;
  int i  = rlocal & 1023;
  const float* dr = dist + (size_t)rlocal*NN;
  unsigned long long key[16];
  #pragma unroll
  for (int m = 0; m < 16; m++){
    int j = m*64 + lane;
    key[m] = ((unsigned long long)fkey(dr[j]) << 32) | (unsigned)j;
  }
  int* op = idxb + (size_t)(((bbase + bl)*NN) + i)*NK;
  for (int round = 0; round < NK; round++){
    unsigned long long best = key[0];
    #pragma unroll
    for (int m = 1; m < 16; m++) best = key[m] < best ? key[m] : best;
    #pragma unroll
    for (int off = 32; off >= 1; off >>= 1){
      unsigned long long o = __shfl_xor(best, off);
      best = o < best ? o : best;
    }
    if (lane == 0) op[round] = (int)(best & 0xFFFFFFFFu);
    int wl = (int)(best & 63u);
    int wm = (int)((best >> 6) & 15u);
    if (lane == wl) key[wm] = ~0ull;
  }
}

// ---------------- K3: Wh per head + f1/f2 ----------------
__global__ __launch_bounds__(256) void k3_wh1(const float* __restrict__ hn,
    const float* __restrict__ W_heads, const float* __restrict__ a_heads,
    float* __restrict__ Wh1, float* __restrict__ f1, float* __restrict__ f2){
  int hh = blockIdx.z, b = blockIdx.y;
  int n = blockIdx.x*256 + threadIdx.x;
  const float* hb = hn + b*NC*NN;
  const float* W = W_heads + hh*NC*NF;
  float wh[NF];
  #pragma unroll
  for (int f = 0; f < NF; f++) wh[f] = 0.f;
  for (int c = 0; c < NC; c++){
    float xv = hb[c*NN + n];
    #pragma unroll
    for (int f = 0; f < NF; f++) wh[f] = fmaf(xv, W[c*NF + f], wh[f]);
  }
  const float* al = a_heads + hh*2*NF;
  float s1 = 0.f, s2 = 0.f;
  #pragma unroll
  for (int f = 0; f < NF; f++){ s1 = fmaf(wh[f], al[f], s1); s2 = fmaf(wh[f], al[NF+f], s2); }
  int hb2 = hh*NB + b;
  float* o = Wh1 + (size_t)((hb2*NN) + n)*16;
  #pragma unroll
  for (int f = 0; f < NF; f++) o[f] = wh[f];
  o[15] = 0.f;
  f1[hb2*NN + n] = s1; f2[hb2*NN + n] = s2;
}

// ---------------- K4: layer-1 edges + column denominators ----------------
__global__ __launch_bounds__(256) void k4_edge1(const int* __restrict__ idxb, const float* __restrict__ f1,
                         const float* __restrict__ f2, float* __restrict__ e1,
                         float* __restrict__ denom1){
  int t = blockIdx.x*256 + threadIdx.x;    // ((hb)*NN + i)*9 + k
  int k = t % 9; int rest = t / 9; int i = rest & 1023; int hb = rest >> 10;
  int b = hb & 15;
  int j = idxb[((b*NN) + i)*NK + k];
  float e = f1[hb*NN + i] + f2[hb*NN + j];
  e = e >= 0.f ? e : 0.2f*e;
  e1[t] = e;
  atomicAdd(denom1 + hb*NN + j, expf(e));
  (void)k;
}

// ---------------- K4b: empty-column uniform correction (layer 1) ----------------
__global__ __launch_bounds__(256) void k4b_u1(const float* __restrict__ denom1,
                       const float* __restrict__ Wh1, float* __restrict__ u1){
  int t = blockIdx.x*256 + threadIdx.x;    // hb*NN + j
  if (denom1[t] != 0.f) return;
  int hb = t >> 10;
  const float* w = Wh1 + (size_t)t*16;
  for (int f = 0; f < NF; f++) atomicAdd(u1 + hb*16 + f, w[f] * (1.f/1024.f));
}

// ---------------- K5: hp1 = att @ Wh, elu, pack into hcat ----------------
__global__ __launch_bounds__(256) void k5_hp1(const int* __restrict__ idxb, const float* __restrict__ e1,
    const float* __restrict__ denom1, const float* __restrict__ Wh1,
    const float* __restrict__ u1, float* __restrict__ hcat){
  int t = blockIdx.x*256 + threadIdx.x;    // hb*NN + i
  int hb = t >> 10, i = t & 1023;
  int b = hb & 15, hh = hb >> 4;
  float acc[NF];
  #pragma unroll
  for (int f = 0; f < NF; f++) acc[f] = u1[hb*16 + f];
  const float* e = e1 + (size_t)t*NK;
  const int* jp = idxb + (size_t)((b*NN) + i)*NK;
  for (int k = 0; k < NK; k++){
    int j = jp[k];
    float att = expf(e[k]) / denom1[hb*NN + j];
    const float4* w = (const float4*)(Wh1 + (size_t)((hb*NN) + j)*16);
    float4 w0 = w[0], w1 = w[1], w2 = w[2], w3 = w[3];
    acc[0]  = fmaf(att, w0.x, acc[0]);  acc[1]  = fmaf(att, w0.y, acc[1]);
    acc[2]  = fmaf(att, w0.z, acc[2]);  acc[3]  = fmaf(att, w0.w, acc[3]);
    acc[4]  = fmaf(att, w1.x, acc[4]);  acc[5]  = fmaf(att, w1.y, acc[5]);
    acc[6]  = fmaf(att, w1.z, acc[6]);  acc[7]  = fmaf(att, w1.w, acc[7]);
    acc[8]  = fmaf(att, w2.x, acc[8]);  acc[9]  = fmaf(att, w2.y, acc[9]);
    acc[10] = fmaf(att, w2.z, acc[10]); acc[11] = fmaf(att, w2.w, acc[11]);
    acc[12] = fmaf(att, w3.x, acc[12]); acc[13] = fmaf(att, w3.y, acc[13]);
    acc[14] = fmaf(att, w3.z, acc[14]);
  }
  float* o = hcat + (size_t)((b*NN) + i)*64 + hh*NF;
  #pragma unroll
  for (int f = 0; f < NF; f++) o[f] = eluf(acc[f]);
}

// ---------------- K7: Wh2 = hcat @ W_out + f1/f2 ----------------
__global__ __launch_bounds__(256) void k7_wh2(const float* __restrict__ hcat,
    const float* __restrict__ W_out, const float* __restrict__ a_out,
    float* __restrict__ Wh2, float* __restrict__ f1, float* __restrict__ f2){
  __shared__ float hcl[64][65];
  __shared__ float p1[4][64], p2[4][64];
  int b = blockIdx.y, n0 = blockIdx.x*64;
  for (int t = threadIdx.x; t < 4096; t += 256){
    int nl = t >> 6, c = t & 63;
    hcl[nl][c] = hcat[(size_t)((b*NN) + n0 + nl)*64 + c];
  }
  __syncthreads();
  int nl = threadIdx.x & 63;
  int wv = threadIdx.x >> 6;
  int og = __builtin_amdgcn_readfirstlane(wv * 16);
  float z[16];
  #pragma unroll
  for (int m = 0; m < 16; m++) z[m] = 0.f;
  for (int c = 0; c < 60; c++){
    float yv = hcl[nl][c];
    #pragma unroll
    for (int m = 0; m < 16; m++) z[m] = fmaf(yv, W_out[c*64 + og + m], z[m]);
  }
  int n = n0 + nl;
  float* o = Wh2 + ((size_t)(b*NN) + n)*64 + og;
  #pragma unroll
  for (int m = 0; m < 16; m += 4) *(float4*)&o[m] = make_float4(z[m],z[m+1],z[m+2],z[m+3]);
  float s1 = 0.f, s2 = 0.f;
  #pragma unroll
  for (int m = 0; m < 16; m++){ s1 = fmaf(z[m], a_out[og+m], s1); s2 = fmaf(z[m], a_out[64+og+m], s2); }
  p1[wv][nl] = s1; p2[wv][nl] = s2;
  __syncthreads();
  if (threadIdx.x < 64){
    f1[b*NN + n0 + threadIdx.x] = p1[0][threadIdx.x] + p1[1][threadIdx.x] + p1[2][threadIdx.x] + p1[3][threadIdx.x];
    f2[b*NN + n0 + threadIdx.x] = p2[0][threadIdx.x] + p2[1][threadIdx.x] + p2[2][threadIdx.x] + p2[3][threadIdx.x];
  }
}

// ---------------- K8: layer-2 edges + denominators ----------------
__global__ __launch_bounds__(256) void k8_edge2(const int* __restrict__ idxb, const float* __restrict__ f1,
                         const float* __restrict__ f2, float* __restrict__ e2,
                         float* __restrict__ denom2){
  int t = blockIdx.x*256 + threadIdx.x;    // (b*NN + i)*9 + k
  int bi = t / 9;
  int b = bi >> 10;
  int j = idxb[t];
  float e = f1[bi] + f2[b*NN + j];
  e = e >= 0.f ? e : 0.2f*e;
  e2[t] = e;
  atomicAdd(denom2 + b*NN + j, expf(e));
}

// ---------------- K8b: empty-column correction (layer 2) ----------------
__global__ __launch_bounds__(256) void k8b_u2(const float* __restrict__ denom2,
                       const float* __restrict__ Wh2, float* __restrict__ u2){
  int t = blockIdx.x*256 + threadIdx.x;    // b*NN + j
  if (denom2[t] != 0.f) return;
  int b = t >> 10;
  const float* w = Wh2 + (size_t)t*64;
  for (int f = 0; f < 64; f++) atomicAdd(u2 + b*64 + f, w[f] * (1.f/1024.f));
}

// ---------------- K9: hp2 -> elu -> leaky(0.01) ----------------
__global__ __launch_bounds__(256) void k9_hp2(const int* __restrict__ idxb, const float* __restrict__ e2,
    const float* __restrict__ denom2, const float* __restrict__ Wh2,
    const float* __restrict__ u2, float* __restrict__ ytil){
  int t = blockIdx.x*256 + threadIdx.x;    // b*NN + i
  int b = t >> 10;
  float acc[64];
  #pragma unroll
  for (int f = 0; f < 64; f++) acc[f] = u2[b*64 + f];
  const float* e = e2 + (size_t)t*NK;
  const int* jp = idxb + (size_t)t*NK;
  for (int k = 0; k < NK; k++){
    int j = jp[k];
    float att = expf(e[k]) / denom2[b*NN + j];
    const float4* w = (const float4*)(Wh2 + (size_t)((b*NN) + j)*64);
    #pragma unroll
    for (int q = 0; q < 16; q++){
      float4 wvv = w[q];
      acc[4*q+0] = fmaf(att, wvv.x, acc[4*q+0]);
      acc[4*q+1] = fmaf(att, wvv.y, acc[4*q+1]);
      acc[4*q+2] = fmaf(att, wvv.z, acc[4*q+2]);
      acc[4*q+3] = fmaf(att, wvv.w, acc[4*q+3]);
    }
  }
  float* o = ytil + (size_t)t*64;
  #pragma unroll
  for (int f = 0; f < 64; f++){
    float v = eluf(acc[f]);
    o[f] = v >= 0.f ? v : 0.01f*v;
  }
}

// ---------------- K11: 1x1 conv + BN + residual ----------------
__global__ __launch_bounds__(256) void k11_conv(const float* __restrict__ ytil,
    const float* __restrict__ conv_w, const float* __restrict__ conv_b,
    const float* __restrict__ bn_g, const float* __restrict__ bn_b,
    const float* __restrict__ x, float* __restrict__ out){
  __shared__ float yt[64][65];
  int b = blockIdx.y, n0 = blockIdx.x*64;
  for (int t = threadIdx.x; t < 4096; t += 256){
    int nl = t >> 6, c = t & 63;
    yt[nl][c] = ytil[(size_t)((b*NN) + n0 + nl)*64 + c];
  }
  __syncthreads();
  int nl = threadIdx.x & 63;
  int og = __builtin_amdgcn_readfirstlane((int)(threadIdx.x >> 6) * 16);
  float z[16];
  #pragma unroll
  for (int m = 0; m < 16; m++) z[m] = 0.f;
  for (int c = 0; c < 64; c++){
    float yv = yt[nl][c];
    #pragma unroll
    for (int m = 0; m < 16; m++) z[m] = fmaf(yv, conv_w[(og+m)*64 + c], z[m]);
  }
  const float scbn = 1.f / sqrtf(1.f + 1e-5f);
  #pragma unroll
  for (int m = 0; m < 16; m++){
    int o = og + m;
    size_t oi = ((size_t)(b*64 + o))*NN + n0 + nl;
    out[oi] = fmaf(z[m] + conv_b[o], bn_g[o]*scbn, bn_b[o]) + x[oi];
  }
}

extern "C" void kernel_launch(void* const* d_in, const int* in_sizes, int n_in,
                              void* d_out, int out_size, void* d_ws, size_t ws_size,
                              hipStream_t stream){
  (void)in_sizes; (void)n_in; (void)out_size; (void)ws_size;
  const float* x       = (const float*)d_in[0];
  const float* W_heads = (const float*)d_in[1];
  const float* a_heads = (const float*)d_in[2];
  const float* W_out   = (const float*)d_in[3];
  const float* a_out   = (const float*)d_in[4];
  const float* conv_w  = (const float*)d_in[5];
  const float* conv_b  = (const float*)d_in[6];
  const float* bn_g    = (const float*)d_in[7];
  const float* bn_b    = (const float*)d_in[8];
  float* ws  = (float*)d_ws;
  float* out = (float*)d_out;

  float* hn   = ws + OFF_HN;
  float* sqv  = ws + OFF_SQV;
  int*   idxb = (int*)(ws + OFF_IDX);
  float* den1 = ws + OFF_DEN1;
  float* u1   = ws + OFF_U1;
  float* den2 = ws + OFF_DEN2;
  float* u2   = ws + OFF_U2;
  float* f11  = ws + OFF_F11;
  float* f21  = ws + OFF_F21;
  float* f12  = ws + OFF_F12;
  float* f22  = ws + OFF_F22;
  float* e1   = ws + OFF_E1;
  float* e2   = ws + OFF_E2;
  float* Wh1  = ws + OFF_WH1;
  float* hcat = ws + OFF_HCAT;
  float* Wh2  = ws + OFF_WH2;
  float* ytil = ws + OFF_YTIL;
  float* dist = ws + OFF_DIST;

  k0_zero<<<dim3(328), dim3(256), 0, stream>>>(ws);
  k1_norm<<<dim3(64), dim3(256), 0, stream>>>(x, hn, sqv);
  for (int bb = 0; bb < NB; bb += 4){
    k2a_dist<<<dim3(64,4), dim3(256), 0, stream>>>(hn, sqv, dist, bb);
    k2b_top9<<<dim3(1024), dim3(256), 0, stream>>>(dist, idxb, bb);
  }
  k3_wh1<<<dim3(4,16,4), dim3(256), 0, stream>>>(hn, W_heads, a_heads, Wh1, f11, f21);
  k4_edge1<<<dim3(2304), dim3(256), 0, stream>>>(idxb, f11, f21, e1, den1);
  k4b_u1<<<dim3(256), dim3(256), 0, stream>>>(den1, Wh1, u1);
  k5_hp1<<<dim3(256), dim3(256), 0, stream>>>(idxb, e1, den1, Wh1, u1, hcat);
  k7_wh2<<<dim3(16,16), dim3(256), 0, stream>>>(hcat, W_out, a_out, Wh2, f12, f22);
  k8_edge2<<<dim3(576), dim3(256), 0, stream>>>(idxb, f12, f22, e2, den2);
  k8b_u2<<<dim3(64), dim3(256), 0, stream>>>(den2, Wh2, u2);
  k9_hp2<<<dim3(64), dim3(256), 0, stream>>>(idxb, e2, den2, Wh2, u2, ytil);
  k11_conv<<<dim3(16,16), dim3(256), 0, stream>>>(ytil, conv_w, conv_b, bn_g, bn_b, x, out);
}

// Round 5
// 314.954 us; speedup vs baseline: 1.1253x; 1.1253x over previous
//
#include <hip/hip_runtime.h>
#include <math.h>

#define NB 16
#define NC 64
#define NN 1024
#define NK 9
#define NH 4
#define NF 15

// ---- workspace layout (float offsets), total 6391808 floats = 24.4 MB ----
#define OFF_HN     0              /* hnorm [16][64][1024] = 1048576 */
#define OFF_SQV    1048576        /* [16*1024] */
#define OFF_IDX    1064960        /* int[16*1024*9] = 147456 */
#define OFF_DEN1   1212416        /* [4*16*1024] */
#define OFF_U1     1277952        /* [4*16*16] */
#define OFF_DEN2   1278976        /* [16*1024] */
#define OFF_U2     1295360        /* [16*64] */
#define OFF_F11    1296384        /* [4*16*1024] */
#define OFF_F21    1361920
#define OFF_F12    1427456        /* [16*1024] */
#define OFF_F22    1443840
#define OFF_E1     1460224        /* [589824] */
#define OFF_E2     2050048        /* [147456] */
#define OFF_BIG    2197504
#define OFF_DIST   OFF_BIG        /* chunk: 4*1024*1024 floats, dead after knn loop */
#define OFF_WH1    OFF_BIG        /* packed [16][1024][64] = 1048576 */
#define OFF_HCAT   3246080        /* [16*1024*64] */
#define OFF_WH2    4294656        /* [16*1024*64] */
#define OFF_YTIL   5343232        /* [16*1024*64] */
#define ZERO_BASE  OFF_DEN1
#define ZERO_LEN   83968          /* den1+u1+den2+u2, contiguous */

__device__ __forceinline__ unsigned fkey(float x){
  unsigned b = __float_as_uint(x);
  return (b & 0x80000000u) ? ~b : (b | 0x80000000u);   // order-preserving float->uint
}
__device__ __forceinline__ float eluf(float x){ return x > 0.f ? x : expm1f(x); }

// ---------------- K1: zero accumulators + h = x / max(||x||,eps) ----------------
// grid 328 blocks: all blocks grid-stride the zero region; blocks 0..63 also do the norm.
__global__ __launch_bounds__(256) void k1_norm(const float* __restrict__ x,
                                               float* __restrict__ hn, float* __restrict__ sqv,
                                               float* __restrict__ ws){
  int t = blockIdx.x*256 + threadIdx.x;
  if (t < ZERO_LEN) ws[ZERO_BASE + t] = 0.f;
  if (t >= NB*NN) return;                   // only first 64 blocks do norm work
  int b = t >> 10, n = t & 1023;
  const float* xb = x + b*NC*NN;
  float* hb = hn + b*NC*NN;
  float s = 0.f;
  #pragma unroll
  for (int c = 0; c < NC; c++){ float v = xb[c*NN + n]; s = fmaf(v, v, s); }
  float nrm = fmaxf(sqrtf(s), 1e-12f);
  float s2 = 0.f;
  #pragma unroll
  for (int c = 0; c < NC; c++){
    float v = xb[c*NN + n] / nrm;           // true IEEE division, like the reference
    hb[c*NN + n] = v;
    s2 = fmaf(v, v, s2);                    // same fmaf chain order as k2a's diag dot
  }
  sqv[t] = s2;
}

// ---------------- K2a: dist tile GEMM (128x128 tile, K=64 staged once) ----------------
__global__ __launch_bounds__(256) void k2a_dist(const float* __restrict__ hn,
    const float* __restrict__ sqv, float* __restrict__ dist, int bbase){
  __shared__ float As[64][128];
  __shared__ float Bs[64][128];
  int b = bbase + blockIdx.y;
  int i0 = (blockIdx.x >> 3) * 128, j0 = (blockIdx.x & 7) * 128;
  const float* hb = hn + b*NC*NN;
  for (int t = threadIdx.x; t < 64*128; t += 256){
    int c = t >> 7, ii = t & 127;
    As[c][ii] = hb[c*NN + i0 + ii];
    Bs[c][ii] = hb[c*NN + j0 + ii];
  }
  __syncthreads();
  int tx = threadIdx.x & 15, ty = threadIdx.x >> 4;
  float acc[8][8];
  #pragma unroll
  for (int q = 0; q < 8; q++)
    #pragma unroll
    for (int jj = 0; jj < 8; jj++) acc[q][jj] = 0.f;
  #pragma unroll 4
  for (int c = 0; c < 64; c++){
    float4 a0 = *(const float4*)&As[c][ty*8];
    float4 a1 = *(const float4*)&As[c][ty*8+4];
    float4 b0 = *(const float4*)&Bs[c][tx*8];
    float4 b1 = *(const float4*)&Bs[c][tx*8+4];
    float av[8], bv[8];
    av[0]=a0.x; av[1]=a0.y; av[2]=a0.z; av[3]=a0.w; av[4]=a1.x; av[5]=a1.y; av[6]=a1.z; av[7]=a1.w;
    bv[0]=b0.x; bv[1]=b0.y; bv[2]=b0.z; bv[3]=b0.w; bv[4]=b1.x; bv[5]=b1.y; bv[6]=b1.z; bv[7]=b1.w;
    #pragma unroll
    for (int q = 0; q < 8; q++)
      #pragma unroll
      for (int jj = 0; jj < 8; jj++) acc[q][jj] = fmaf(av[q], bv[jj], acc[q][jj]);
  }
  const float* sv = sqv + b*NN;
  float sj[8];
  #pragma unroll
  for (int jj = 0; jj < 8; jj++) sj[jj] = sv[j0 + tx*8 + jj];
  #pragma unroll
  for (int q = 0; q < 8; q++){
    float si = sv[i0 + ty*8 + q];
    float o0[8];
    #pragma unroll
    for (int jj = 0; jj < 8; jj++) o0[jj] = (si - 2.f*acc[q][jj]) + sj[jj];  // exact +0 on diag
    float* dp = dist + (size_t)((blockIdx.y*NN) + i0 + ty*8 + q)*NN + j0 + tx*8;
    *(float4*)&dp[0] = make_float4(o0[0],o0[1],o0[2],o0[3]);
    *(float4*)&dp[4] = make_float4(o0[4],o0[5],o0[6],o0[7]);
  }
}

// ---------------- K2b: top-9 per row (wave-resident u64 keys, stable ties) ----------------
__global__ __launch_bounds__(256) void k2b_top9(const float* __restrict__ dist,
                                                int* __restrict__ idxb, int bbase){
  int wave = threadIdx.x >> 6, lane = threadIdx.x & 63;
  int rlocal = blockIdx.x*4 + wave;          // chunk-local row (4 batches * 1024)
  int bl = rlocal >> 10;
  int i  = rlocal & 1023;
  const float* dr = dist + (size_t)rlocal*NN;
  unsigned long long key[16];
  #pragma unroll
  for (int m = 0; m < 16; m++){
    int j = m*64 + lane;
    key[m] = ((unsigned long long)fkey(dr[j]) << 32) | (unsigned)j;
  }
  int* op = idxb + (size_t)(((bbase + bl)*NN) + i)*NK;
  for (int round = 0; round < NK; round++){
    unsigned long long best = key[0];
    #pragma unroll
    for (int m = 1; m < 16; m++) best = key[m] < best ? key[m] : best;
    #pragma unroll
    for (int off = 32; off >= 1; off >>= 1){
      unsigned long long o = __shfl_xor(best, off);
      best = o < best ? o : best;
    }
    if (lane == 0) op[round] = (int)(best & 0xFFFFFFFFu);
    int wl = (int)(best & 63u);
    int wm = (int)((best >> 6) & 15u);
    if (lane == wl) key[wm] = ~0ull;
  }
}

// ---------------- K3: Wh all 4 heads in one pass + f1/f2 (packed Wh1 [b][n][hh*16+f]) ----------------
__global__ __launch_bounds__(256) void k3_wh1(const float* __restrict__ hn,
    const float* __restrict__ W_heads, const float* __restrict__ a_heads,
    float* __restrict__ Wh1, float* __restrict__ f1, float* __restrict__ f2){
  int b = blockIdx.y;
  int n = blockIdx.x*256 + threadIdx.x;
  const float* hb = hn + b*NC*NN;
  float wh[NH][NF];
  #pragma unroll
  for (int hh = 0; hh < NH; hh++)
    #pragma unroll
    for (int f = 0; f < NF; f++) wh[hh][f] = 0.f;
  for (int c = 0; c < NC; c++){
    float xv = hb[c*NN + n];
    #pragma unroll
    for (int hh = 0; hh < NH; hh++){
      const float* W = W_heads + (hh*NC + c)*NF;
      #pragma unroll
      for (int f = 0; f < NF; f++) wh[hh][f] = fmaf(xv, W[f], wh[hh][f]);
    }
  }
  float* orow = Wh1 + ((size_t)(b*NN) + n)*64;
  #pragma unroll
  for (int hh = 0; hh < NH; hh++){
    const float* al = a_heads + hh*2*NF;
    float s1 = 0.f, s2 = 0.f;
    #pragma unroll
    for (int f = 0; f < NF; f++){ s1 = fmaf(wh[hh][f], al[f], s1); s2 = fmaf(wh[hh][f], al[NF+f], s2); }
    float4* o4 = (float4*)(orow + hh*16);
    o4[0] = make_float4(wh[hh][0], wh[hh][1], wh[hh][2], wh[hh][3]);
    o4[1] = make_float4(wh[hh][4], wh[hh][5], wh[hh][6], wh[hh][7]);
    o4[2] = make_float4(wh[hh][8], wh[hh][9], wh[hh][10], wh[hh][11]);
    o4[3] = make_float4(wh[hh][12], wh[hh][13], wh[hh][14], 0.f);
    int hb2 = hh*NB + b;
    f1[hb2*NN + n] = s1; f2[hb2*NN + n] = s2;
  }
}

// ---------------- K4: layer-1 edges + column denominators ----------------
__global__ __launch_bounds__(256) void k4_edge1(const int* __restrict__ idxb, const float* __restrict__ f1,
                         const float* __restrict__ f2, float* __restrict__ e1,
                         float* __restrict__ denom1){
  int t = blockIdx.x*256 + threadIdx.x;    // ((hb)*NN + i)*9 + k
  int k = t % 9; int rest = t / 9; int i = rest & 1023; int hb = rest >> 10;
  int b = hb & 15;
  int j = idxb[((b*NN) + i)*NK + k];
  float e = f1[hb*NN + i] + f2[hb*NN + j];
  e = e >= 0.f ? e : 0.2f*e;
  e1[t] = e;
  atomicAdd(denom1 + hb*NN + j, expf(e));
  (void)k;
}

// ---------------- K4b: empty-column uniform correction (layer 1) ----------------
__global__ __launch_bounds__(256) void k4b_u1(const float* __restrict__ denom1,
                       const float* __restrict__ Wh1, float* __restrict__ u1){
  int t = blockIdx.x*256 + threadIdx.x;    // hb*NN + j
  if (denom1[t] != 0.f) return;
  int hb = t >> 10, j = t & 1023;
  int hh = hb >> 4, b = hb & 15;
  const float* w = Wh1 + ((size_t)(b*NN) + j)*64 + hh*16;
  for (int f = 0; f < NF; f++) atomicAdd(u1 + hb*16 + f, w[f] * (1.f/1024.f));
}

// ---------------- K5: hp1 = att @ Wh (wave-per-row, lane=(head,f)) ----------------
__global__ __launch_bounds__(256) void k5_hp1(const int* __restrict__ idxb, const float* __restrict__ e1,
    const float* __restrict__ denom1, const float* __restrict__ Wh1,
    const float* __restrict__ u1, float* __restrict__ hcat){
  int wave = threadIdx.x >> 6, lane = threadIdx.x & 63;
  int t = blockIdx.x*4 + wave;             // b*NN + i
  int b = t >> 10, i = t & 1023;
  int hh = lane >> 4, f = lane & 15;
  int hb = hh*NB + b;
  float acc = u1[hb*16 + f];               // slot 15 is zeroed
  const int* jp = idxb + (size_t)t*NK;
  const float* ep = e1 + (size_t)(hb*NN + i)*NK;
  const float* dn = denom1 + hb*NN;
  const float* wbase = Wh1 + ((size_t)(b*NN))*64;
  #pragma unroll 3
  for (int k = 0; k < NK; k++){
    int j = jp[k];
    float att = expf(ep[k]) / dn[j];
    acc = fmaf(att, wbase[(size_t)j*64 + lane], acc);
  }
  if (f < NF) hcat[((size_t)(b*NN) + i)*64 + hh*NF + f] = eluf(acc);
}

// ---------------- K7: Wh2 = hcat @ W_out + f1/f2 ----------------
__global__ __launch_bounds__(256) void k7_wh2(const float* __restrict__ hcat,
    const float* __restrict__ W_out, const float* __restrict__ a_out,
    float* __restrict__ Wh2, float* __restrict__ f1, float* __restrict__ f2){
  __shared__ float hcl[64][65];
  __shared__ float p1[4][64], p2[4][64];
  int b = blockIdx.y, n0 = blockIdx.x*64;
  for (int t = threadIdx.x; t < 4096; t += 256){
    int nl = t >> 6, c = t & 63;
    hcl[nl][c] = hcat[(size_t)((b*NN) + n0 + nl)*64 + c];
  }
  __syncthreads();
  int nl = threadIdx.x & 63;
  int wv = threadIdx.x >> 6;
  int og = __builtin_amdgcn_readfirstlane(wv * 16);
  float z[16];
  #pragma unroll
  for (int m = 0; m < 16; m++) z[m] = 0.f;
  for (int c = 0; c < 60; c++){
    float yv = hcl[nl][c];
    #pragma unroll
    for (int m = 0; m < 16; m++) z[m] = fmaf(yv, W_out[c*64 + og + m], z[m]);
  }
  int n = n0 + nl;
  float* o = Wh2 + ((size_t)(b*NN) + n)*64 + og;
  #pragma unroll
  for (int m = 0; m < 16; m += 4) *(float4*)&o[m] = make_float4(z[m],z[m+1],z[m+2],z[m+3]);
  float s1 = 0.f, s2 = 0.f;
  #pragma unroll
  for (int m = 0; m < 16; m++){ s1 = fmaf(z[m], a_out[og+m], s1); s2 = fmaf(z[m], a_out[64+og+m], s2); }
  p1[wv][nl] = s1; p2[wv][nl] = s2;
  __syncthreads();
  if (threadIdx.x < 64){
    f1[b*NN + n0 + threadIdx.x] = p1[0][threadIdx.x] + p1[1][threadIdx.x] + p1[2][threadIdx.x] + p1[3][threadIdx.x];
    f2[b*NN + n0 + threadIdx.x] = p2[0][threadIdx.x] + p2[1][threadIdx.x] + p2[2][threadIdx.x] + p2[3][threadIdx.x];
  }
}

// ---------------- K8: layer-2 edges + denominators ----------------
__global__ __launch_bounds__(256) void k8_edge2(const int* __restrict__ idxb, const float* __restrict__ f1,
                         const float* __restrict__ f2, float* __restrict__ e2,
                         float* __restrict__ denom2){
  int t = blockIdx.x*256 + threadIdx.x;    // (b*NN + i)*9 + k
  int bi = t / 9;
  int b = bi >> 10;
  int j = idxb[t];
  float e = f1[bi] + f2[b*NN + j];
  e = e >= 0.f ? e : 0.2f*e;
  e2[t] = e;
  atomicAdd(denom2 + b*NN + j, expf(e));
}

// ---------------- K8b: empty-column correction (layer 2) ----------------
__global__ __launch_bounds__(256) void k8b_u2(const float* __restrict__ denom2,
                       const float* __restrict__ Wh2, float* __restrict__ u2){
  int t = blockIdx.x*256 + threadIdx.x;    // b*NN + j
  if (denom2[t] != 0.f) return;
  int b = t >> 10;
  const float* w = Wh2 + (size_t)t*64;
  for (int f = 0; f < 64; f++) atomicAdd(u2 + b*64 + f, w[f] * (1.f/1024.f));
}

// ---------------- K9: hp2 -> elu -> leaky(0.01) (wave-per-row, lane=channel) ----------------
__global__ __launch_bounds__(256) void k9_hp2(const int* __restrict__ idxb, const float* __restrict__ e2,
    const float* __restrict__ denom2, const float* __restrict__ Wh2,
    const float* __restrict__ u2, float* __restrict__ ytil){
  int wave = threadIdx.x >> 6, lane = threadIdx.x & 63;
  int t = blockIdx.x*4 + wave;             // b*NN + i
  int b = t >> 10;
  float acc = u2[b*64 + lane];
  const int* jp = idxb + (size_t)t*NK;
  const float* ep = e2 + (size_t)t*NK;
  const float* dn = denom2 + b*NN;
  const float* wbase = Wh2 + ((size_t)(b*NN))*64;
  #pragma unroll 3
  for (int k = 0; k < NK; k++){
    int j = jp[k];
    float att = expf(ep[k]) / dn[j];
    acc = fmaf(att, wbase[(size_t)j*64 + lane], acc);
  }
  float v = eluf(acc);
  ytil[(size_t)t*64 + lane] = v >= 0.f ? v : 0.01f*v;
}

// ---------------- K11: 1x1 conv + BN + residual ----------------
__global__ __launch_bounds__(256) void k11_conv(const float* __restrict__ ytil,
    const float* __restrict__ conv_w, const float* __restrict__ conv_b,
    const float* __restrict__ bn_g, const float* __restrict__ bn_b,
    const float* __restrict__ x, float* __restrict__ out){
  __shared__ float yt[64][65];
  int b = blockIdx.y, n0 = blockIdx.x*64;
  for (int t = threadIdx.x; t < 4096; t += 256){
    int nl = t >> 6, c = t & 63;
    yt[nl][c] = ytil[(size_t)((b*NN) + n0 + nl)*64 + c];
  }
  __syncthreads();
  int nl = threadIdx.x & 63;
  int og = __builtin_amdgcn_readfirstlane((int)(threadIdx.x >> 6) * 16);
  float z[16];
  #pragma unroll
  for (int m = 0; m < 16; m++) z[m] = 0.f;
  for (int c = 0; c < 64; c++){
    float yv = yt[nl][c];
    #pragma unroll
    for (int m = 0; m < 16; m++) z[m] = fmaf(yv, conv_w[(og+m)*64 + c], z[m]);
  }
  const float scbn = 1.f / sqrtf(1.f + 1e-5f);
  #pragma unroll
  for (int m = 0; m < 16; m++){
    int o = og + m;
    size_t oi = ((size_t)(b*64 + o))*NN + n0 + nl;
    out[oi] = fmaf(z[m] + conv_b[o], bn_g[o]*scbn, bn_b[o]) + x[oi];
  }
}

extern "C" void kernel_launch(void* const* d_in, const int* in_sizes, int n_in,
                              void* d_out, int out_size, void* d_ws, size_t ws_size,
                              hipStream_t stream){
  (void)in_sizes; (void)n_in; (void)out_size; (void)ws_size;
  const float* x       = (const float*)d_in[0];
  const float* W_heads = (const float*)d_in[1];
  const float* a_heads = (const float*)d_in[2];
  const float* W_out   = (const float*)d_in[3];
  const float* a_out   = (const float*)d_in[4];
  const float* conv_w  = (const float*)d_in[5];
  const float* conv_b  = (const float*)d_in[6];
  const float* bn_g    = (const float*)d_in[7];
  const float* bn_b    = (const float*)d_in[8];
  float* ws  = (float*)d_ws;
  float* out = (float*)d_out;

  float* hn   = ws + OFF_HN;
  float* sqv  = ws + OFF_SQV;
  int*   idxb = (int*)(ws + OFF_IDX);
  float* den1 = ws + OFF_DEN1;
  float* u1   = ws + OFF_U1;
  float* den2 = ws + OFF_DEN2;
  float* u2   = ws + OFF_U2;
  float* f11  = ws + OFF_F11;
  float* f21  = ws + OFF_F21;
  float* f12  = ws + OFF_F12;
  float* f22  = ws + OFF_F22;
  float* e1   = ws + OFF_E1;
  float* e2   = ws + OFF_E2;
  float* Wh1  = ws + OFF_WH1;
  float* hcat = ws + OFF_HCAT;
  float* Wh2  = ws + OFF_WH2;
  float* ytil = ws + OFF_YTIL;
  float* dist = ws + OFF_DIST;

  k1_norm<<<dim3(328), dim3(256), 0, stream>>>(x, hn, sqv, ws);
  for (int bb = 0; bb < NB; bb += 4){
    k2a_dist<<<dim3(64,4), dim3(256), 0, stream>>>(hn, sqv, dist, bb);
    k2b_top9<<<dim3(1024), dim3(256), 0, stream>>>(dist, idxb, bb);
  }
  k3_wh1<<<dim3(4,16), dim3(256), 0, stream>>>(hn, W_heads, a_heads, Wh1, f11, f21);
  k4_edge1<<<dim3(2304), dim3(256), 0, stream>>>(idxb, f11, f21, e1, den1);
  k4b_u1<<<dim3(256), dim3(256), 0, stream>>>(den1, Wh1, u1);
  k5_hp1<<<dim3(4096), dim3(256), 0, stream>>>(idxb, e1, den1, Wh1, u1, hcat);
  k7_wh2<<<dim3(16,16), dim3(256), 0, stream>>>(hcat, W_out, a_out, Wh2, f12, f22);
  k8_edge2<<<dim3(576), dim3(256), 0, stream>>>(idxb, f12, f22, e2, den2);
  k8b_u2<<<dim3(64), dim3(256), 0, stream>>>(den2, Wh2, u2);
  k9_hp2<<<dim3(4096), dim3(256), 0, stream>>>(idxb, e2, den2, Wh2, u2, ytil);
  k11_conv<<<dim3(16,16), dim3(256), 0, stream>>>(ytil, conv_w, conv_b, bn_g, bn_b, x, out);
}

// Round 6
// 270.277 us; speedup vs baseline: 1.3113x; 1.1653x over previous
//
#include <hip/hip_runtime.h>
#include <math.h>

#define NB 16
#define NC 64
#define NN 1024
#define NK 9
#define NH 4
#define NF 15

// ---- workspace layout (float offsets), total 23169024 floats = 88.4 MB (ws is ~268 MB) ----
#define OFF_HN     0              /* hnorm [16][64][1024] = 1048576 */
#define OFF_SQV    1048576        /* [16*1024] */
#define OFF_IDX    1064960        /* int[16*1024*9] = 147456 */
#define OFF_DEN1   1212416        /* [4*16*1024] */
#define OFF_U1     1277952        /* [4*16*16] */
#define OFF_DEN2   1278976        /* [16*1024] */
#define OFF_U2     1295360        /* [16*64] */
#define OFF_F11    1296384        /* [4*16*1024] */
#define OFF_F21    1361920
#define OFF_F12    1427456        /* [16*1024] */
#define OFF_F22    1443840
#define OFF_E1     1460224        /* [589824] */
#define OFF_E2     2050048        /* [147456] */
#define OFF_WH1    2197504        /* packed [16][1024][64] = 1048576 */
#define OFF_HCAT   3246080        /* [16*1024*64] */
#define OFF_WH2    4294656        /* [16*1024*64] */
#define OFF_YTIL   5343232        /* [16*1024*64] */
#define OFF_DIST   6391808        /* [16*1024*1024] = 16777216, full 64 MB */
#define ZERO_BASE  OFF_DEN1
#define ZERO_LEN   83968          /* den1+u1+den2+u2, contiguous */

__device__ __forceinline__ unsigned fkey(float x){
  unsigned b = __float_as_uint(x);
  return (b & 0x80000000u) ? ~b : (b | 0x80000000u);   // order-preserving float->uint
}
__device__ __forceinline__ float eluf(float x){ return x > 0.f ? x : expm1f(x); }

// ---------------- K1: zero accumulators + h = x/max(||x||,eps) + Wh (all heads) + f1/f2 ----
// grid 328 blocks: all blocks zero the accumulator region; blocks 0..63 do norm+Wh work.
__global__ __launch_bounds__(256) void k1_norm_wh(const float* __restrict__ x,
    const float* __restrict__ W_heads, const float* __restrict__ a_heads,
    float* __restrict__ hn, float* __restrict__ sqv, float* __restrict__ Wh1,
    float* __restrict__ f1, float* __restrict__ f2, float* __restrict__ ws){
  int t = blockIdx.x*256 + threadIdx.x;
  if (t < ZERO_LEN) ws[ZERO_BASE + t] = 0.f;
  if (t >= NB*NN) return;                   // only first 64 blocks continue
  int b = t >> 10, n = t & 1023;
  const float* xb = x + b*NC*NN;
  float* hb = hn + b*NC*NN;
  float s = 0.f;
  #pragma unroll
  for (int c = 0; c < NC; c++){ float v = xb[c*NN + n]; s = fmaf(v, v, s); }
  float nrm = fmaxf(sqrtf(s), 1e-12f);
  float wh[NH][NF];
  #pragma unroll
  for (int hh = 0; hh < NH; hh++)
    #pragma unroll
    for (int f = 0; f < NF; f++) wh[hh][f] = 0.f;
  float s2 = 0.f;
  for (int c = 0; c < NC; c++){
    float v = xb[c*NN + n] / nrm;           // true IEEE division, like the reference
    hb[c*NN + n] = v;
    s2 = fmaf(v, v, s2);                    // same fmaf chain order as k2a's diag dot
    #pragma unroll
    for (int hh = 0; hh < NH; hh++){
      const float* W = W_heads + (hh*NC + c)*NF;
      #pragma unroll
      for (int f = 0; f < NF; f++) wh[hh][f] = fmaf(v, W[f], wh[hh][f]);
    }
  }
  sqv[t] = s2;
  float* orow = Wh1 + ((size_t)(b*NN) + n)*64;
  #pragma unroll
  for (int hh = 0; hh < NH; hh++){
    const float* al = a_heads + hh*2*NF;
    float s1 = 0.f, sb = 0.f;
    #pragma unroll
    for (int f = 0; f < NF; f++){ s1 = fmaf(wh[hh][f], al[f], s1); sb = fmaf(wh[hh][f], al[NF+f], sb); }
    float4* o4 = (float4*)(orow + hh*16);
    o4[0] = make_float4(wh[hh][0], wh[hh][1], wh[hh][2], wh[hh][3]);
    o4[1] = make_float4(wh[hh][4], wh[hh][5], wh[hh][6], wh[hh][7]);
    o4[2] = make_float4(wh[hh][8], wh[hh][9], wh[hh][10], wh[hh][11]);
    o4[3] = make_float4(wh[hh][12], wh[hh][13], wh[hh][14], 0.f);
    int hb2 = hh*NB + b;
    f1[hb2*NN + n] = s1; f2[hb2*NN + n] = sb;
  }
}

// ---------------- K2a: dist tile GEMM, ALL batches one dispatch (grid 64 x 16) ----------------
__global__ __launch_bounds__(256) void k2a_dist(const float* __restrict__ hn,
    const float* __restrict__ sqv, float* __restrict__ dist){
  __shared__ float As[64][128];
  __shared__ float Bs[64][128];
  int b = blockIdx.y;
  int i0 = (blockIdx.x >> 3) * 128, j0 = (blockIdx.x & 7) * 128;
  const float* hb = hn + b*NC*NN;
  for (int t = threadIdx.x; t < 64*128; t += 256){
    int c = t >> 7, ii = t & 127;
    As[c][ii] = hb[c*NN + i0 + ii];
    Bs[c][ii] = hb[c*NN + j0 + ii];
  }
  __syncthreads();
  int tx = threadIdx.x & 15, ty = threadIdx.x >> 4;
  float acc[8][8];
  #pragma unroll
  for (int q = 0; q < 8; q++)
    #pragma unroll
    for (int jj = 0; jj < 8; jj++) acc[q][jj] = 0.f;
  #pragma unroll 4
  for (int c = 0; c < 64; c++){
    float4 a0 = *(const float4*)&As[c][ty*8];
    float4 a1 = *(const float4*)&As[c][ty*8+4];
    float4 b0 = *(const float4*)&Bs[c][tx*8];
    float4 b1 = *(const float4*)&Bs[c][tx*8+4];
    float av[8], bv[8];
    av[0]=a0.x; av[1]=a0.y; av[2]=a0.z; av[3]=a0.w; av[4]=a1.x; av[5]=a1.y; av[6]=a1.z; av[7]=a1.w;
    bv[0]=b0.x; bv[1]=b0.y; bv[2]=b0.z; bv[3]=b0.w; bv[4]=b1.x; bv[5]=b1.y; bv[6]=b1.z; bv[7]=b1.w;
    #pragma unroll
    for (int q = 0; q < 8; q++)
      #pragma unroll
      for (int jj = 0; jj < 8; jj++) acc[q][jj] = fmaf(av[q], bv[jj], acc[q][jj]);
  }
  const float* sv = sqv + b*NN;
  float sj[8];
  #pragma unroll
  for (int jj = 0; jj < 8; jj++) sj[jj] = sv[j0 + tx*8 + jj];
  #pragma unroll
  for (int q = 0; q < 8; q++){
    float si = sv[i0 + ty*8 + q];
    float o0[8];
    #pragma unroll
    for (int jj = 0; jj < 8; jj++) o0[jj] = (si - 2.f*acc[q][jj]) + sj[jj];  // exact +0 on diag
    float* dp = dist + (size_t)((b*NN) + i0 + ty*8 + q)*NN + j0 + tx*8;
    *(float4*)&dp[0] = make_float4(o0[0],o0[1],o0[2],o0[3]);
    *(float4*)&dp[4] = make_float4(o0[4],o0[5],o0[6],o0[7]);
  }
}

// ---------------- K2b: top-9 per row + layer-1 edges + den1 atomics (fused) ----------------
__global__ __launch_bounds__(256) void k2b_top9e(const float* __restrict__ dist,
    int* __restrict__ idxb, const float* __restrict__ f1, const float* __restrict__ f2,
    float* __restrict__ e1, float* __restrict__ den1){
  __shared__ int sj[4][16];
  int wave = threadIdx.x >> 6, lane = threadIdx.x & 63;
  int t = blockIdx.x*4 + wave;               // b*NN + i, 0..16383
  int b = t >> 10, i = t & 1023;
  const float* dr = dist + (size_t)t*NN;
  unsigned long long key[16];
  #pragma unroll
  for (int m = 0; m < 16; m++){
    int j = m*64 + lane;
    key[m] = ((unsigned long long)fkey(dr[j]) << 32) | (unsigned)j;
  }
  for (int round = 0; round < NK; round++){
    unsigned long long best = key[0];
    #pragma unroll
    for (int m = 1; m < 16; m++) best = key[m] < best ? key[m] : best;
    #pragma unroll
    for (int off = 32; off >= 1; off >>= 1){
      unsigned long long o = __shfl_xor(best, off);
      best = o < best ? o : best;
    }
    if (lane == 0) sj[wave][round] = (int)(best & 0xFFFFFFFFu);
    int wl = (int)(best & 63u);
    int wm = (int)((best >> 6) & 15u);
    if (lane == wl) key[wm] = ~0ull;
  }
  __syncthreads();                           // make sj visible (no early returns above)
  if (lane < NK) idxb[(size_t)t*NK + lane] = sj[wave][lane];
  if (lane < 36){
    int k = lane >> 2, hh = lane & 3;
    int j = sj[wave][k];
    int hb = hh*NB + b;
    float e = f1[hb*NN + i] + f2[hb*NN + j];
    e = e >= 0.f ? e : 0.2f*e;
    e1[(size_t)(hb*NN + i)*NK + k] = e;
    atomicAdd(den1 + hb*NN + j, expf(e));
  }
}

// ---------------- K4b: empty-column uniform correction (layer 1) ----------------
__global__ __launch_bounds__(256) void k4b_u1(const float* __restrict__ denom1,
                       const float* __restrict__ Wh1, float* __restrict__ u1){
  int t = blockIdx.x*256 + threadIdx.x;    // hb*NN + j
  if (denom1[t] != 0.f) return;
  int hb = t >> 10, j = t & 1023;
  int hh = hb >> 4, b = hb & 15;
  const float* w = Wh1 + ((size_t)(b*NN) + j)*64 + hh*16;
  for (int f = 0; f < NF; f++) atomicAdd(u1 + hb*16 + f, w[f] * (1.f/1024.f));
}

// ---------------- K5: hp1 = att @ Wh (wave-per-row, lane=(head,f)) ----------------
__global__ __launch_bounds__(256) void k5_hp1(const int* __restrict__ idxb, const float* __restrict__ e1,
    const float* __restrict__ denom1, const float* __restrict__ Wh1,
    const float* __restrict__ u1, float* __restrict__ hcat){
  int wave = threadIdx.x >> 6, lane = threadIdx.x & 63;
  int t = blockIdx.x*4 + wave;             // b*NN + i
  int b = t >> 10, i = t & 1023;
  int hh = lane >> 4, f = lane & 15;
  int hb = hh*NB + b;
  float acc = u1[hb*16 + f];               // slot 15 is zeroed
  const int* jp = idxb + (size_t)t*NK;
  const float* ep = e1 + (size_t)(hb*NN + i)*NK;
  const float* dn = denom1 + hb*NN;
  const float* wbase = Wh1 + ((size_t)(b*NN))*64;
  #pragma unroll 3
  for (int k = 0; k < NK; k++){
    int j = jp[k];
    float att = expf(ep[k]) / dn[j];
    acc = fmaf(att, wbase[(size_t)j*64 + lane], acc);
  }
  if (f < NF) hcat[((size_t)(b*NN) + i)*64 + hh*NF + f] = eluf(acc);
}

// ---------------- K7: Wh2 = hcat @ W_out + f1/f2 ----------------
__global__ __launch_bounds__(256) void k7_wh2(const float* __restrict__ hcat,
    const float* __restrict__ W_out, const float* __restrict__ a_out,
    float* __restrict__ Wh2, float* __restrict__ f1, float* __restrict__ f2){
  __shared__ float hcl[64][65];
  __shared__ float p1[4][64], p2[4][64];
  int b = blockIdx.y, n0 = blockIdx.x*64;
  for (int t = threadIdx.x; t < 4096; t += 256){
    int nl = t >> 6, c = t & 63;
    hcl[nl][c] = hcat[(size_t)((b*NN) + n0 + nl)*64 + c];
  }
  __syncthreads();
  int nl = threadIdx.x & 63;
  int wv = threadIdx.x >> 6;
  int og = __builtin_amdgcn_readfirstlane(wv * 16);
  float z[16];
  #pragma unroll
  for (int m = 0; m < 16; m++) z[m] = 0.f;
  for (int c = 0; c < 60; c++){
    float yv = hcl[nl][c];
    #pragma unroll
    for (int m = 0; m < 16; m++) z[m] = fmaf(yv, W_out[c*64 + og + m], z[m]);
  }
  int n = n0 + nl;
  float* o = Wh2 + ((size_t)(b*NN) + n)*64 + og;
  #pragma unroll
  for (int m = 0; m < 16; m += 4) *(float4*)&o[m] = make_float4(z[m],z[m+1],z[m+2],z[m+3]);
  float s1 = 0.f, s2 = 0.f;
  #pragma unroll
  for (int m = 0; m < 16; m++){ s1 = fmaf(z[m], a_out[og+m], s1); s2 = fmaf(z[m], a_out[64+og+m], s2); }
  p1[wv][nl] = s1; p2[wv][nl] = s2;
  __syncthreads();
  if (threadIdx.x < 64){
    f1[b*NN + n0 + threadIdx.x] = p1[0][threadIdx.x] + p1[1][threadIdx.x] + p1[2][threadIdx.x] + p1[3][threadIdx.x];
    f2[b*NN + n0 + threadIdx.x] = p2[0][threadIdx.x] + p2[1][threadIdx.x] + p2[2][threadIdx.x] + p2[3][threadIdx.x];
  }
}

// ---------------- K8: layer-2 edges + denominators ----------------
__global__ __launch_bounds__(256) void k8_edge2(const int* __restrict__ idxb, const float* __restrict__ f1,
                         const float* __restrict__ f2, float* __restrict__ e2,
                         float* __restrict__ denom2){
  int t = blockIdx.x*256 + threadIdx.x;    // (b*NN + i)*9 + k
  int bi = t / 9;
  int b = bi >> 10;
  int j = idxb[t];
  float e = f1[bi] + f2[b*NN + j];
  e = e >= 0.f ? e : 0.2f*e;
  e2[t] = e;
  atomicAdd(denom2 + b*NN + j, expf(e));
}

// ---------------- K8b: empty-column correction (layer 2) ----------------
__global__ __launch_bounds__(256) void k8b_u2(const float* __restrict__ denom2,
                       const float* __restrict__ Wh2, float* __restrict__ u2){
  int t = blockIdx.x*256 + threadIdx.x;    // b*NN + j
  if (denom2[t] != 0.f) return;
  int b = t >> 10;
  const float* w = Wh2 + (size_t)t*64;
  for (int f = 0; f < 64; f++) atomicAdd(u2 + b*64 + f, w[f] * (1.f/1024.f));
}

// ---------------- K9: hp2 -> elu -> leaky(0.01) (wave-per-row, lane=channel) ----------------
__global__ __launch_bounds__(256) void k9_hp2(const int* __restrict__ idxb, const float* __restrict__ e2,
    const float* __restrict__ denom2, const float* __restrict__ Wh2,
    const float* __restrict__ u2, float* __restrict__ ytil){
  int wave = threadIdx.x >> 6, lane = threadIdx.x & 63;
  int t = blockIdx.x*4 + wave;             // b*NN + i
  int b = t >> 10;
  float acc = u2[b*64 + lane];
  const int* jp = idxb + (size_t)t*NK;
  const float* ep = e2 + (size_t)t*NK;
  const float* dn = denom2 + b*NN;
  const float* wbase = Wh2 + ((size_t)(b*NN))*64;
  #pragma unroll 3
  for (int k = 0; k < NK; k++){
    int j = jp[k];
    float att = expf(ep[k]) / dn[j];
    acc = fmaf(att, wbase[(size_t)j*64 + lane], acc);
  }
  float v = eluf(acc);
  ytil[(size_t)t*64 + lane] = v >= 0.f ? v : 0.01f*v;
}

// ---------------- K11: 1x1 conv + BN + residual ----------------
__global__ __launch_bounds__(256) void k11_conv(const float* __restrict__ ytil,
    const float* __restrict__ conv_w, const float* __restrict__ conv_b,
    const float* __restrict__ bn_g, const float* __restrict__ bn_b,
    const float* __restrict__ x, float* __restrict__ out){
  __shared__ float yt[64][65];
  int b = blockIdx.y, n0 = blockIdx.x*64;
  for (int t = threadIdx.x; t < 4096; t += 256){
    int nl = t >> 6, c = t & 63;
    yt[nl][c] = ytil[(size_t)((b*NN) + n0 + nl)*64 + c];
  }
  __syncthreads();
  int nl = threadIdx.x & 63;
  int og = __builtin_amdgcn_readfirstlane((int)(threadIdx.x >> 6) * 16);
  float z[16];
  #pragma unroll
  for (int m = 0; m < 16; m++) z[m] = 0.f;
  for (int c = 0; c < 64; c++){
    float yv = yt[nl][c];
    #pragma unroll
    for (int m = 0; m < 16; m++) z[m] = fmaf(yv, conv_w[(og+m)*64 + c], z[m]);
  }
  const float scbn = 1.f / sqrtf(1.f + 1e-5f);
  #pragma unroll
  for (int m = 0; m < 16; m++){
    int o = og + m;
    size_t oi = ((size_t)(b*64 + o))*NN + n0 + nl;
    out[oi] = fmaf(z[m] + conv_b[o], bn_g[o]*scbn, bn_b[o]) + x[oi];
  }
}

extern "C" void kernel_launch(void* const* d_in, const int* in_sizes, int n_in,
                              void* d_out, int out_size, void* d_ws, size_t ws_size,
                              hipStream_t stream){
  (void)in_sizes; (void)n_in; (void)out_size; (void)ws_size;
  const float* x       = (const float*)d_in[0];
  const float* W_heads = (const float*)d_in[1];
  const float* a_heads = (const float*)d_in[2];
  const float* W_out   = (const float*)d_in[3];
  const float* a_out   = (const float*)d_in[4];
  const float* conv_w  = (const float*)d_in[5];
  const float* conv_b  = (const float*)d_in[6];
  const float* bn_g    = (const float*)d_in[7];
  const float* bn_b    = (const float*)d_in[8];
  float* ws  = (float*)d_ws;
  float* out = (float*)d_out;

  float* hn   = ws + OFF_HN;
  float* sqv  = ws + OFF_SQV;
  int*   idxb = (int*)(ws + OFF_IDX);
  float* den1 = ws + OFF_DEN1;
  float* u1   = ws + OFF_U1;
  float* den2 = ws + OFF_DEN2;
  float* u2   = ws + OFF_U2;
  float* f11  = ws + OFF_F11;
  float* f21  = ws + OFF_F21;
  float* f12  = ws + OFF_F12;
  float* f22  = ws + OFF_F22;
  float* e1   = ws + OFF_E1;
  float* e2   = ws + OFF_E2;
  float* Wh1  = ws + OFF_WH1;
  float* hcat = ws + OFF_HCAT;
  float* Wh2  = ws + OFF_WH2;
  float* ytil = ws + OFF_YTIL;
  float* dist = ws + OFF_DIST;

  k1_norm_wh<<<dim3(328), dim3(256), 0, stream>>>(x, W_heads, a_heads, hn, sqv, Wh1, f11, f21, ws);
  k2a_dist<<<dim3(64,16), dim3(256), 0, stream>>>(hn, sqv, dist);
  k2b_top9e<<<dim3(4096), dim3(256), 0, stream>>>(dist, idxb, f11, f21, e1, den1);
  k4b_u1<<<dim3(256), dim3(256), 0, stream>>>(den1, Wh1, u1);
  k5_hp1<<<dim3(4096), dim3(256), 0, stream>>>(idxb, e1, den1, Wh1, u1, hcat);
  k7_wh2<<<dim3(16,16), dim3(256), 0, stream>>>(hcat, W_out, a_out, Wh2, f12, f22);
  k8_edge2<<<dim3(576), dim3(256), 0, stream>>>(idxb, f12, f22, e2, den2);
  k8b_u2<<<dim3(64), dim3(256), 0, stream>>>(den2, Wh2, u2);
  k9_hp2<<<dim3(4096), dim3(256), 0, stream>>>(idxb, e2, den2, Wh2, u2, ytil);
  k11_conv<<<dim3(16,16), dim3(256), 0, stream>>>(ytil, conv_w, conv_b, bn_g, bn_b, x, out);
}